// Round 3
// baseline (394.787 us; speedup 1.0000x reference)
//
#include <hip/hip_runtime.h>
#include <cstddef>

#define NH   8
#define NB   4
#define HD   32
#define NPIX 4096
#define NBATCH 8
#define NL   300
#define D    256

// ---------------- Kernel 1: value projection (f32 GEMM 32768x256x256) ----------------
// vm[b][h][pix][d] = mask ? 0 : value[b][pix][:] . vproj_w[h*32+d][:] + vproj_b
__global__ __launch_bounds__(256)
void vproj_kernel(const float* __restrict__ value, const float* __restrict__ W,
                  const float* __restrict__ bias, const unsigned char* __restrict__ mask,
                  float* __restrict__ vm)
{
    __shared__ float As[16][65];
    __shared__ float Bs[16][65];
    const int bm = blockIdx.x, bn = blockIdx.y;
    const int tid = threadIdx.x;
    const int tr = tid >> 4, tc = tid & 15;
    float acc[4][4] = {};
    const int row0 = bm * 64, col0 = bn * 64;
    for (int k0 = 0; k0 < D; k0 += 16) {
        #pragma unroll
        for (int i = 0; i < 4; ++i) {
            int idx = tid + i * 256;
            int r = idx >> 4, kk = idx & 15;
            As[kk][r] = value[(size_t)(row0 + r) * D + k0 + kk];
            Bs[kk][r] = W[(size_t)(col0 + r) * D + k0 + kk];
        }
        __syncthreads();
        #pragma unroll
        for (int kk = 0; kk < 16; ++kk) {
            float a[4], bv[4];
            #pragma unroll
            for (int i = 0; i < 4; ++i) a[i] = As[kk][tr * 4 + i];
            #pragma unroll
            for (int j = 0; j < 4; ++j) bv[j] = Bs[kk][tc * 4 + j];
            #pragma unroll
            for (int i = 0; i < 4; ++i)
                #pragma unroll
                for (int j = 0; j < 4; ++j)
                    acc[i][j] += a[i] * bv[j];
        }
        __syncthreads();
    }
    #pragma unroll
    for (int i = 0; i < 4; ++i) {
        int row = row0 + tr * 4 + i;
        int bb = row >> 12, pix = row & (NPIX - 1);
        float m = (mask[row] != 0) ? 0.0f : 1.0f;
        #pragma unroll
        for (int j = 0; j < 4; ++j) {
            int col = col0 + tc * 4 + j;
            int h = col >> 5, dd = col & 31;
            vm[(((size_t)(bb * NH + h) * NPIX) + pix) * HD + dd] = m * (acc[i][j] + bias[col]);
        }
    }
}

// ---------------- Kernel 2: box + attn projections (GEMV, per-query) ----------------
__global__ __launch_bounds__(128)
void proj_kernel(const float* __restrict__ query,
                 const float* __restrict__ box_w, const float* __restrict__ box_b,
                 const float* __restrict__ attn_w, const float* __restrict__ attn_b,
                 float* __restrict__ bp, float* __restrict__ ap, float* __restrict__ aw_out)
{
    __shared__ float q[D];
    const int blk = blockIdx.x;   // b*NL + l
    const int tid = threadIdx.x;  // 0..127
    q[tid]       = query[(size_t)blk * D + tid];
    q[tid + 128] = query[(size_t)blk * D + tid + 128];
    __syncthreads();
    float accb = box_b[tid], acca = attn_b[tid];
    const float* bw  = box_w  + (size_t)tid * D;
    const float* awp = attn_w + (size_t)tid * D;
    for (int c = 0; c < D; ++c) {
        accb += q[c] * bw[c];
        acca += q[c] * awp[c];
    }
    bp[(size_t)blk * 128 + tid] = accb;
    ap[(size_t)blk * 128 + tid] = acca;

    // Output 2 is the REPEATED aw: (b,l1,NH,NB,4,4), awrep[..,ii,jj] = raw[..,ii>>1,jj>>1]
    // tid = h*16 + box*4 + r*2 + c  ->  write to 4 positions (2r+{0,1}, 2c+{0,1})
    const int h   = tid >> 4;
    const int box = (tid >> 2) & 3;
    const int r   = (tid >> 1) & 1;
    const int c   = tid & 1;
    float* awq = aw_out + (size_t)blk * 512 + (size_t)(h * NB + box) * 16;
    #pragma unroll
    for (int di = 0; di < 2; ++di)
        #pragma unroll
        for (int dj = 0; dj < 2; ++dj)
            awq[(2 * r + di) * 4 + (2 * c + dj)] = acca;
}

// ---------------- Kernel 3: softmax weights + bilinear sampling + weighted sum ----------
__global__ __launch_bounds__(256)
void sample_kernel(const float* __restrict__ vm, const float* __restrict__ bp,
                   const float* __restrict__ ap, const float* __restrict__ ref_windows,
                   const float* __restrict__ vratio, const int* __restrict__ vshape,
                   float* __restrict__ outp, float* __restrict__ moutp)
{
    __shared__ float sbp[128], sap[128], sref[4];
    const int blk = blockIdx.x;   // b*NL + l
    const int tid = threadIdx.x;  // 0..255
    const int bb = blk / NL;
    const int h = tid >> 5, dd = tid & 31;
    if (tid < 128) { sbp[tid] = bp[(size_t)blk * 128 + tid]; sap[tid] = ap[(size_t)blk * 128 + tid]; }
    if (tid < 4) sref[tid] = ref_windows[(size_t)blk * 4 + tid];
    __syncthreads();
    const int Hf = vshape[0], Wf = vshape[1];
    const float Hff = (float)Hf, Wff = (float)Wf;
    const float vr0 = vratio[bb * 2 + 0], vr1 = vratio[bb * 2 + 1];

    // softmax prep from the 16 distinct attn logits for this head
    float aw16[16];
    #pragma unroll
    for (int k = 0; k < 16; ++k) aw16[k] = sap[h * 16 + k];
    float mx = aw16[0];
    #pragma unroll
    for (int k = 1; k < 16; ++k) mx = fmaxf(mx, aw16[k]);
    float e16[16]; float ssum = 0.f;
    #pragma unroll
    for (int k = 0; k < 16; ++k) { e16[k] = expf(aw16[k] - mx); ssum += e16[k]; }
    ssum *= 4.0f;   // each raw logit repeats 4x in the 64-wide spatial softmax
    float ld[4];
    #pragma unroll
    for (int c = 0; c < 4; ++c) ld[c] = e16[c] + e16[4 + c] + e16[8 + c] + e16[12 + c];

    const float kidx[4] = {-0.375f, -0.125f, 0.125f, 0.375f};
    float acc = 0.f, accm = 0.f;
    const float* vmh = vm + ((size_t)(bb * NH + h) * NPIX) * HD + dd;

    #pragma unroll
    for (int box = 0; box < NB; ++box) {
        const float o0 = sbp[h * 16 + box * 4 + 0];
        const float o1 = sbp[h * 16 + box * 4 + 1];
        const float o2 = sbp[h * 16 + box * 4 + 2];
        const float o3 = sbp[h * 16 + box * 4 + 3];
        const float cx  = sref[0] + o0 * 0.125f * sref[2];
        const float cy  = sref[1] + o1 * 0.125f * sref[3];
        const float bw_ = sref[2] + o2 * 0.125f * sref[2];
        const float bh_ = sref[3] + o3 * 0.125f * sref[3];
        const float rw = fmaxf(bw_, 0.f), rh = fmaxf(bh_, 0.f);
        #pragma unroll
        for (int ii = 0; ii < 4; ++ii) {
            const float gy = (cy + kidx[ii] * rh) * vr1;
            const float y = gy * Hff - 0.5f;
            const float y0f = floorf(y);
            const int iy0 = (int)y0f;
            const float wy1 = y - y0f, wy0 = 1.f - wy1;
            #pragma unroll
            for (int jj = 0; jj < 4; ++jj) {
                const float gx = (cx + kidx[jj] * rw) * vr0;
                const float x = gx * Wff - 0.5f;
                const float x0f = floorf(x);
                const int ix0 = (int)x0f;
                const float wx1 = x - x0f, wx0 = 1.f - wx1;
                float samp = 0.f;
                #pragma unroll
                for (int cyi = 0; cyi < 2; ++cyi) {
                    const int yi = iy0 + cyi;
                    const float wy = cyi ? wy1 : wy0;
                    const bool yin = (yi >= 0) && (yi < Hf);
                    const int yc = min(max(yi, 0), Hf - 1);
                    #pragma unroll
                    for (int cxi = 0; cxi < 2; ++cxi) {
                        const int xi = ix0 + cxi;
                        const float wx = cxi ? wx1 : wx0;
                        const bool xin = (xi >= 0) && (xi < Wf);
                        const int xc = min(max(xi, 0), Wf - 1);
                        const float wgt = (yin && xin) ? (wy * wx) : 0.f;
                        const float v = vmh[(size_t)(yc * Wf + xc) * HD];
                        samp += v * wgt;
                    }
                }
                const int kpos = (ii >> 1) * 2 + (jj >> 1);
                const float ev = e16[box * 4 + kpos];
                acc  += samp * (ev / ssum);
                accm += samp * (ev / ld[kpos]);
            }
        }
    }
    outp[(size_t)blk * 256 + h * 32 + dd]  = acc;
    moutp[(size_t)blk * 256 + h * 32 + dd] = accm;
}

// ---------------- Kernel 4: output projection (both outputs share W) ----------------
// NOTE: outp/moutp may ALIAS out1/out2 — each block reads its own 256 floats
// into LDS, syncs, then overwrites exactly that range. Disjoint across blocks.
__global__ __launch_bounds__(256)
void oproj_kernel(const float* __restrict__ outp, const float* __restrict__ moutp,
                  const float* __restrict__ W, const float* __restrict__ bias,
                  float* __restrict__ out1, float* __restrict__ out2)
{
    __shared__ float r1[256], r2[256];
    const int blk = blockIdx.x;
    const int tid = threadIdx.x;
    r1[tid] = outp[(size_t)blk * 256 + tid];
    r2[tid] = moutp[(size_t)blk * 256 + tid];
    __syncthreads();
    float a1 = bias[tid], a2 = bias[tid];
    const float* wr = W + (size_t)tid * 256;
    for (int v = 0; v < 256; ++v) {
        const float wv = wr[v];
        a1 += r1[v] * wv;
        a2 += r2[v] * wv;
    }
    out1[(size_t)blk * 256 + tid] = a1;
    out2[(size_t)blk * 256 + tid] = a2;
}

extern "C" void kernel_launch(void* const* d_in, const int* in_sizes, int n_in,
                              void* d_out, int out_size, void* d_ws, size_t ws_size,
                              hipStream_t stream)
{
    const float* query        = (const float*)d_in[0];
    const float* value        = (const float*)d_in[1];
    const int*   vshape       = (const int*)d_in[2];   // integers arrive as int32
    const unsigned char* vmask= (const unsigned char*)d_in[3];
    // d_in[4] = v_start_index (unused)
    const float* vratio       = (const float*)d_in[5];
    const float* refw         = (const float*)d_in[6];
    const float* box_w        = (const float*)d_in[7];
    const float* box_b        = (const float*)d_in[8];
    const float* attn_w       = (const float*)d_in[9];
    const float* attn_b       = (const float*)d_in[10];
    const float* vproj_w      = (const float*)d_in[11];
    const float* vproj_b      = (const float*)d_in[12];
    const float* oproj_w      = (const float*)d_in[13];
    const float* oproj_b      = (const float*)d_in[14];

    float* ws    = (float*)d_ws;
    float* vm    = ws;                    // 8*8*4096*32 = 8,388,608 f32 (33.5 MB)
    float* bp    = vm + 8388608;          // 307,200
    float* ap    = bp + 307200;           // 307,200

    float* out1 = (float*)d_out;          // output       614,400
    float* out2 = out1 + 614400;          // mask_output  614,400
    float* awo  = out2 + 614400;          // aw (REPEATED 4x4) 1,228,800

    // scratch for pre-projection accumulators aliases the final output region
    float* outp  = out1;
    float* moutp = out2;

    vproj_kernel<<<dim3(512, 4), 256, 0, stream>>>(value, vproj_w, vproj_b, vmask, vm);
    proj_kernel<<<NBATCH * NL, 128, 0, stream>>>(query, box_w, box_b, attn_w, attn_b, bp, ap, awo);
    sample_kernel<<<NBATCH * NL, 256, 0, stream>>>(vm, bp, ap, refw, vratio, vshape, outp, moutp);
    oproj_kernel<<<NBATCH * NL, 256, 0, stream>>>(outp, moutp, oproj_w, oproj_b, out1, out2);
}

// Round 4
// 239.498 us; speedup vs baseline: 1.6484x; 1.6484x over previous
//
#include <hip/hip_runtime.h>
#include <cstddef>

#define NH   8
#define NB   4
#define HD   32
#define NPIX 4096
#define NBATCH 8
#define NL   300
#define D    256
#define NQ   (NBATCH * NL)          // 2400
#define NR   (2 * NQ)               // 4800 stacked rows for oproj

typedef __attribute__((ext_vector_type(4))) float  f32x4;
typedef __attribute__((ext_vector_type(8))) short  bf16x8;

__device__ __forceinline__ unsigned short f2bf(float f) {
    union { float f; unsigned u; } v; v.f = f;
    unsigned r = v.u + 0x7fffu + ((v.u >> 16) & 1u);   // round-to-nearest-even
    return (unsigned short)(r >> 16);
}

__device__ __forceinline__ bf16x8 pack8(const f32x4 a, const f32x4 b) {
    bf16x8 w;
    w[0] = (short)f2bf(a[0]); w[1] = (short)f2bf(a[1]);
    w[2] = (short)f2bf(a[2]); w[3] = (short)f2bf(a[3]);
    w[4] = (short)f2bf(b[0]); w[5] = (short)f2bf(b[1]);
    w[6] = (short)f2bf(b[2]); w[7] = (short)f2bf(b[3]);
    return w;
}

// ---------------- Kernel 1: value projection, bf16 MFMA (32768x256 @ 256x256^T) ---------
// C rows = (b,pix), C cols = out-dim (h*32+dd). W row-major [out][in] = B^T layout.
__global__ __launch_bounds__(256)
void vproj_mfma(const float* __restrict__ value, const float* __restrict__ W,
                const float* __restrict__ bias, const unsigned char* __restrict__ mask,
                float* __restrict__ vm)
{
    __shared__ short As[128][72];   // 64 k + 8 pad (bank-conflict-free ds_read_b128)
    __shared__ short Bs[128][72];
    const int tid  = threadIdx.x;
    const int lane = tid & 63, wid = tid >> 6;
    const int wm = wid >> 1, wn = wid & 1;          // 2x2 wave grid, 64x64 each
    const int row0 = blockIdx.x * 128, col0 = blockIdx.y * 128;
    const int l16 = lane & 15, lg = lane >> 4;

    f32x4 acc[4][4] = {};

    const int ar = tid >> 1;            // 0..127 (tile row)
    const int ak = (tid & 1) * 32;      // k-half

    for (int k0 = 0; k0 < D; k0 += 64) {
        const f32x4* pa = (const f32x4*)(value + (size_t)(row0 + ar) * D + k0 + ak);
        const f32x4* pb = (const f32x4*)(W     + (size_t)(col0 + ar) * D + k0 + ak);
        #pragma unroll
        for (int j = 0; j < 4; ++j) {
            *(bf16x8*)&As[ar][ak + j * 8] = pack8(pa[2 * j], pa[2 * j + 1]);
            *(bf16x8*)&Bs[ar][ak + j * 8] = pack8(pb[2 * j], pb[2 * j + 1]);
        }
        __syncthreads();
        #pragma unroll
        for (int kk = 0; kk < 2; ++kk) {
            bf16x8 af[4], bfr[4];
            #pragma unroll
            for (int m = 0; m < 4; ++m)
                af[m] = *(const bf16x8*)&As[wm * 64 + m * 16 + l16][kk * 32 + lg * 8];
            #pragma unroll
            for (int n = 0; n < 4; ++n)
                bfr[n] = *(const bf16x8*)&Bs[wn * 64 + n * 16 + l16][kk * 32 + lg * 8];
            #pragma unroll
            for (int m = 0; m < 4; ++m)
                #pragma unroll
                for (int n = 0; n < 4; ++n)
                    acc[m][n] = __builtin_amdgcn_mfma_f32_16x16x32_bf16(af[m], bfr[n], acc[m][n], 0, 0, 0);
        }
        __syncthreads();
    }
    // epilogue: C/D layout col=lane&15, row=(lane>>4)*4+reg  [m89 verified]
    #pragma unroll
    for (int m = 0; m < 4; ++m) {
        #pragma unroll
        for (int r = 0; r < 4; ++r) {
            const int grow = row0 + wm * 64 + m * 16 + lg * 4 + r;
            const int bb = grow >> 12, pix = grow & (NPIX - 1);
            const float mf = (mask[grow] != 0) ? 0.f : 1.f;
            #pragma unroll
            for (int n = 0; n < 4; ++n) {
                const int gcol = col0 + wn * 64 + n * 16 + l16;
                const int h = gcol >> 5, dd = gcol & 31;
                vm[((size_t)(bb * NH + h) * NPIX + pix) * HD + dd] = mf * (acc[m][n][r] + bias[gcol]);
            }
        }
    }
}

// ---------------- Kernel 2: box+attn projection as tiled f32 GEMM (2400x256x256) --------
// B cols 0..127 = box_w rows, 128..255 = attn_w rows. Fused bias + aw-repeat epilogue.
__global__ __launch_bounds__(256)
void proj_gemm(const float* __restrict__ query,
               const float* __restrict__ box_w, const float* __restrict__ box_b,
               const float* __restrict__ attn_w, const float* __restrict__ attn_b,
               float* __restrict__ bp, float* __restrict__ ap, float* __restrict__ awo)
{
    __shared__ float As[16][65];
    __shared__ float Bs[16][65];
    const int tid = threadIdx.x;
    const int tr = tid >> 4, tc = tid & 15;
    float acc[4][4] = {};
    const int row0 = blockIdx.x * 64, col0 = blockIdx.y * 64;
    for (int k0 = 0; k0 < D; k0 += 16) {
        #pragma unroll
        for (int i = 0; i < 4; ++i) {
            int idx = tid + i * 256;
            int r = idx >> 4, kk = idx & 15;
            int qrow = min(row0 + r, NQ - 1);
            As[kk][r] = query[(size_t)qrow * D + k0 + kk];
            int c256 = col0 + r;
            const float* src = (c256 < 128) ? (box_w + (size_t)c256 * D)
                                            : (attn_w + (size_t)(c256 - 128) * D);
            Bs[kk][r] = src[k0 + kk];
        }
        __syncthreads();
        #pragma unroll
        for (int kk = 0; kk < 16; ++kk) {
            float a[4], bv[4];
            #pragma unroll
            for (int i = 0; i < 4; ++i) a[i] = As[kk][tr * 4 + i];
            #pragma unroll
            for (int j = 0; j < 4; ++j) bv[j] = Bs[kk][tc * 4 + j];
            #pragma unroll
            for (int i = 0; i < 4; ++i)
                #pragma unroll
                for (int j = 0; j < 4; ++j)
                    acc[i][j] += a[i] * bv[j];
        }
        __syncthreads();
    }
    #pragma unroll
    for (int i = 0; i < 4; ++i) {
        int q = row0 + tr * 4 + i;
        if (q >= NQ) continue;
        #pragma unroll
        for (int j = 0; j < 4; ++j) {
            int col = col0 + tc * 4 + j;
            if (col < 128) {
                bp[(size_t)q * 128 + col] = acc[i][j] + box_b[col];
            } else {
                int rc = col - 128;
                float val = acc[i][j] + attn_b[rc];
                ap[(size_t)q * 128 + rc] = val;
                int h = rc >> 4, bx = (rc >> 2) & 3, rr = (rc >> 1) & 1, cc = rc & 1;
                float* awq = awo + (size_t)q * 512 + (size_t)(h * NB + bx) * 16;
                awq[(2 * rr + 0) * 4 + 2 * cc + 0] = val;
                awq[(2 * rr + 0) * 4 + 2 * cc + 1] = val;
                awq[(2 * rr + 1) * 4 + 2 * cc + 0] = val;
                awq[(2 * rr + 1) * 4 + 2 * cc + 1] = val;
            }
        }
    }
}

// ---------------- Kernel 3: softmax weights + bilinear sampling + weighted sum ----------
__global__ __launch_bounds__(256)
void sample_kernel(const float* __restrict__ vm, const float* __restrict__ bp,
                   const float* __restrict__ ap, const float* __restrict__ ref_windows,
                   const float* __restrict__ vratio, const int* __restrict__ vshape,
                   float* __restrict__ outp, float* __restrict__ moutp)
{
    __shared__ float sbp[128], sap[128], sref[4];
    const int blk = blockIdx.x;   // b*NL + l
    const int tid = threadIdx.x;  // 0..255
    const int bb = blk / NL;
    const int h = tid >> 5, dd = tid & 31;
    if (tid < 128) { sbp[tid] = bp[(size_t)blk * 128 + tid]; sap[tid] = ap[(size_t)blk * 128 + tid]; }
    if (tid < 4) sref[tid] = ref_windows[(size_t)blk * 4 + tid];
    __syncthreads();
    const int Hf = vshape[0], Wf = vshape[1];
    const float Hff = (float)Hf, Wff = (float)Wf;
    const float vr0 = vratio[bb * 2 + 0], vr1 = vratio[bb * 2 + 1];

    float aw16[16];
    #pragma unroll
    for (int k = 0; k < 16; ++k) aw16[k] = sap[h * 16 + k];
    float mx = aw16[0];
    #pragma unroll
    for (int k = 1; k < 16; ++k) mx = fmaxf(mx, aw16[k]);
    float e16[16]; float ssum = 0.f;
    #pragma unroll
    for (int k = 0; k < 16; ++k) { e16[k] = expf(aw16[k] - mx); ssum += e16[k]; }
    ssum *= 4.0f;
    float ld[4];
    #pragma unroll
    for (int c = 0; c < 4; ++c) ld[c] = e16[c] + e16[4 + c] + e16[8 + c] + e16[12 + c];

    const float kidx[4] = {-0.375f, -0.125f, 0.125f, 0.375f};
    float acc = 0.f, accm = 0.f;
    const float* vmh = vm + ((size_t)(bb * NH + h) * NPIX) * HD + dd;

    #pragma unroll
    for (int box = 0; box < NB; ++box) {
        const float o0 = sbp[h * 16 + box * 4 + 0];
        const float o1 = sbp[h * 16 + box * 4 + 1];
        const float o2 = sbp[h * 16 + box * 4 + 2];
        const float o3 = sbp[h * 16 + box * 4 + 3];
        const float cx  = sref[0] + o0 * 0.125f * sref[2];
        const float cy  = sref[1] + o1 * 0.125f * sref[3];
        const float bw_ = sref[2] + o2 * 0.125f * sref[2];
        const float bh_ = sref[3] + o3 * 0.125f * sref[3];
        const float rw = fmaxf(bw_, 0.f), rh = fmaxf(bh_, 0.f);
        #pragma unroll
        for (int ii = 0; ii < 4; ++ii) {
            const float gy = (cy + kidx[ii] * rh) * vr1;
            const float y = gy * Hff - 0.5f;
            const float y0f = floorf(y);
            const int iy0 = (int)y0f;
            const float wy1 = y - y0f, wy0 = 1.f - wy1;
            #pragma unroll
            for (int jj = 0; jj < 4; ++jj) {
                const float gx = (cx + kidx[jj] * rw) * vr0;
                const float x = gx * Wff - 0.5f;
                const float x0f = floorf(x);
                const int ix0 = (int)x0f;
                const float wx1 = x - x0f, wx0 = 1.f - wx1;
                float samp = 0.f;
                #pragma unroll
                for (int cyi = 0; cyi < 2; ++cyi) {
                    const int yi = iy0 + cyi;
                    const float wy = cyi ? wy1 : wy0;
                    const bool yin = (yi >= 0) && (yi < Hf);
                    const int yc = min(max(yi, 0), Hf - 1);
                    #pragma unroll
                    for (int cxi = 0; cxi < 2; ++cxi) {
                        const int xi = ix0 + cxi;
                        const float wx = cxi ? wx1 : wx0;
                        const bool xin = (xi >= 0) && (xi < Wf);
                        const int xc = min(max(xi, 0), Wf - 1);
                        const float wgt = (yin && xin) ? (wy * wx) : 0.f;
                        const float v = vmh[(size_t)(yc * Wf + xc) * HD];
                        samp += v * wgt;
                    }
                }
                const int kpos = (ii >> 1) * 2 + (jj >> 1);
                const float ev = e16[box * 4 + kpos];
                acc  += samp * (ev / ssum);
                accm += samp * (ev / ld[kpos]);
            }
        }
    }
    outp[(size_t)blk * 256 + h * 32 + dd]  = acc;
    moutp[(size_t)blk * 256 + h * 32 + dd] = accm;
}

// ---------------- Kernel 4: output projection, bf16 MFMA, stacked A, IN-PLACE -----------
// R = d_out rows 0..4799 (outp rows 0..2399, moutp rows 2400..4799). C written in place.
// Safe: BN=256 full width -> each block reads only its own 128 rows, writes them in the
// epilogue after all K-steps; row-tiles disjoint across blocks.
__global__ __launch_bounds__(512)
void oproj_mfma(const float* __restrict__ R, const float* __restrict__ W,
                const float* __restrict__ bias, float* __restrict__ Out)
{
    __shared__ short As[128][72];
    __shared__ short Bs[256][72];
    const int tid  = threadIdx.x;
    const int lane = tid & 63, wid = tid >> 6;      // 8 waves
    const int wm = wid >> 2, wn = wid & 3;          // 2x4 wave grid, 64x64 each
    const int row0 = blockIdx.x * 128;
    const int l16 = lane & 15, lg = lane >> 4;

    f32x4 acc[4][4] = {};

    const int arr = tid >> 2;            // 0..127
    const int ark = (tid & 3) * 16;      // 0/16/32/48
    const int brr = tid >> 1;            // 0..255
    const int brk = (tid & 1) * 32;      // 0/32

    for (int k0 = 0; k0 < D; k0 += 64) {
        const int arow = min(row0 + arr, NR - 1);
        const f32x4* pa = (const f32x4*)(R + (size_t)arow * D + k0 + ark);
        #pragma unroll
        for (int j = 0; j < 2; ++j)
            *(bf16x8*)&As[arr][ark + j * 8] = pack8(pa[2 * j], pa[2 * j + 1]);
        const f32x4* pb = (const f32x4*)(W + (size_t)brr * D + k0 + brk);
        #pragma unroll
        for (int j = 0; j < 4; ++j)
            *(bf16x8*)&Bs[brr][brk + j * 8] = pack8(pb[2 * j], pb[2 * j + 1]);
        __syncthreads();
        #pragma unroll
        for (int kk = 0; kk < 2; ++kk) {
            bf16x8 af[4], bfr[4];
            #pragma unroll
            for (int m = 0; m < 4; ++m)
                af[m] = *(const bf16x8*)&As[wm * 64 + m * 16 + l16][kk * 32 + lg * 8];
            #pragma unroll
            for (int n = 0; n < 4; ++n)
                bfr[n] = *(const bf16x8*)&Bs[wn * 64 + n * 16 + l16][kk * 32 + lg * 8];
            #pragma unroll
            for (int m = 0; m < 4; ++m)
                #pragma unroll
                for (int n = 0; n < 4; ++n)
                    acc[m][n] = __builtin_amdgcn_mfma_f32_16x16x32_bf16(af[m], bfr[n], acc[m][n], 0, 0, 0);
        }
        __syncthreads();
    }
    #pragma unroll
    for (int m = 0; m < 4; ++m) {
        #pragma unroll
        for (int r = 0; r < 4; ++r) {
            const int grow = row0 + wm * 64 + m * 16 + lg * 4 + r;
            if (grow >= NR) continue;
            #pragma unroll
            for (int n = 0; n < 4; ++n) {
                const int gcol = wn * 64 + n * 16 + l16;
                Out[(size_t)grow * D + gcol] = acc[m][n][r] + bias[gcol];
            }
        }
    }
}

extern "C" void kernel_launch(void* const* d_in, const int* in_sizes, int n_in,
                              void* d_out, int out_size, void* d_ws, size_t ws_size,
                              hipStream_t stream)
{
    const float* query        = (const float*)d_in[0];
    const float* value        = (const float*)d_in[1];
    const int*   vshape       = (const int*)d_in[2];
    const unsigned char* vmask= (const unsigned char*)d_in[3];
    const float* vratio       = (const float*)d_in[5];
    const float* refw         = (const float*)d_in[6];
    const float* box_w        = (const float*)d_in[7];
    const float* box_b        = (const float*)d_in[8];
    const float* attn_w       = (const float*)d_in[9];
    const float* attn_b       = (const float*)d_in[10];
    const float* vproj_w      = (const float*)d_in[11];
    const float* vproj_b      = (const float*)d_in[12];
    const float* oproj_w      = (const float*)d_in[13];
    const float* oproj_b      = (const float*)d_in[14];

    float* ws = (float*)d_ws;
    float* vm = ws;                       // 8,388,608 f32 (33.5 MB)
    float* bp = vm + 8388608;             // 307,200
    float* ap = bp + 307200;              // 307,200

    float* out1 = (float*)d_out;          // output       614,400
    float* out2 = out1 + 614400;          // mask_output  614,400
    float* awo  = out2 + 614400;          // aw repeated  1,228,800

    // pre-projection accumulators live in the output region (stacked 4800x256)
    float* outp  = out1;
    float* moutp = out2;

    vproj_mfma<<<dim3(256, 2), 256, 0, stream>>>(value, vproj_w, vproj_b, vmask, vm);
    proj_gemm<<<dim3(38, 4), 256, 0, stream>>>(query, box_w, box_b, attn_w, attn_b, bp, ap, awo);
    sample_kernel<<<NQ, 256, 0, stream>>>(vm, bp, ap, refw, vratio, vshape, outp, moutp);
    oproj_mfma<<<38, 512, 0, stream>>>(out1, oproj_w, oproj_b, out1);
}

// Round 6
// 215.951 us; speedup vs baseline: 1.8281x; 1.1090x over previous
//
#include <hip/hip_runtime.h>
#include <cstddef>

#define NH   8
#define NB   4
#define HD   32
#define NPIX 4096
#define NBATCH 8
#define NL   300
#define D    256
#define NQ   (NBATCH * NL)          // 2400
#define NR   (2 * NQ)               // 4800 stacked rows for oproj

typedef __attribute__((ext_vector_type(4))) float  f32x4;
typedef __attribute__((ext_vector_type(8))) short  bf16x8;

__device__ __forceinline__ unsigned short f2bf(float f) {
    union { float f; unsigned u; } v; v.f = f;
    unsigned r = v.u + 0x7fffu + ((v.u >> 16) & 1u);   // round-to-nearest-even
    return (unsigned short)(r >> 16);
}
__device__ __forceinline__ float bf2f(unsigned short u) {
    union { unsigned u; float f; } v; v.u = ((unsigned)u) << 16; return v.f;
}
__device__ __forceinline__ bf16x8 pack8(const f32x4 a, const f32x4 b) {
    bf16x8 w;
    w[0] = (short)f2bf(a[0]); w[1] = (short)f2bf(a[1]);
    w[2] = (short)f2bf(a[2]); w[3] = (short)f2bf(a[3]);
    w[4] = (short)f2bf(b[0]); w[5] = (short)f2bf(b[1]);
    w[6] = (short)f2bf(b[2]); w[7] = (short)f2bf(b[3]);
    return w;
}

// ---------------- Kernel 0: one-time f32 -> bf16 conversion (value + vproj_w) ----------
__global__ __launch_bounds__(256)
void tobf16_kernel(const float* __restrict__ value, const float* __restrict__ W,
                   unsigned short* __restrict__ vb, unsigned short* __restrict__ wb)
{
    const int i = blockIdx.x * 256 + threadIdx.x;       // 4096*256 threads, 8 elems each
    {
        const size_t off = (size_t)i * 8;
        f32x4 a = *(const f32x4*)(value + off);
        f32x4 b = *(const f32x4*)(value + off + 4);
        *(bf16x8*)(vb + off) = pack8(a, b);
    }
    if (i < 8192) {                                      // 65,536 W elems
        const size_t off = (size_t)i * 8;
        f32x4 a = *(const f32x4*)(W + off);
        f32x4 b = *(const f32x4*)(W + off + 4);
        *(bf16x8*)(wb + off) = pack8(a, b);
    }
}

// ---------------- Kernel 1: value projection, LDS-free direct-global bf16 MFMA ----------
// Tile 64(M) x 256(N full width): value read ONCE. A frags have no intra-block reuse,
// B (128 KB bf16) is L2-resident -> stream both straight into MFMA regs.
__global__ __launch_bounds__(256)
void vproj_mfma(const unsigned short* __restrict__ Vb, const unsigned short* __restrict__ Wb,
                const float* __restrict__ bias, const unsigned char* __restrict__ mask,
                unsigned short* __restrict__ vm)
{
    const int tid  = threadIdx.x;
    const int lane = tid & 63, wid = tid >> 6;
    const int wm = wid >> 1, wn = wid & 1;      // 2x2 wave grid; wave tile 32(M) x 128(N)
    const int row0 = blockIdx.x * 64;
    const int l16 = lane & 15, lg = lane >> 4;  // A/B frag: row/col = l16, k = lg*8..+7

    f32x4 acc[2][8] = {};
    const unsigned short* pa0 = Vb + (size_t)(row0 + wm * 32 + l16) * D + lg * 8;
    const unsigned short* pb0 = Wb + (size_t)(wn * 128 + l16) * D + lg * 8;

    #pragma unroll
    for (int ks = 0; ks < 8; ++ks) {            // K = 256, 32 per step
        bf16x8 af[2], bfr[8];
        #pragma unroll
        for (int m = 0; m < 2; ++m) af[m]  = *(const bf16x8*)(pa0 + (size_t)m * 16 * D + ks * 32);
        #pragma unroll
        for (int n = 0; n < 8; ++n) bfr[n] = *(const bf16x8*)(pb0 + (size_t)n * 16 * D + ks * 32);
        #pragma unroll
        for (int m = 0; m < 2; ++m)
            #pragma unroll
            for (int n = 0; n < 8; ++n)
                acc[m][n] = __builtin_amdgcn_mfma_f32_16x16x32_bf16(af[m], bfr[n], acc[m][n], 0, 0, 0);
    }
    // C/D layout: col = lane&15, row = (lane>>4)*4 + reg
    #pragma unroll
    for (int m = 0; m < 2; ++m) {
        #pragma unroll
        for (int r = 0; r < 4; ++r) {
            const int grow = row0 + wm * 32 + m * 16 + lg * 4 + r;
            const int bb = grow >> 12, pix = grow & (NPIX - 1);
            const float mf = (mask[grow] != 0) ? 0.f : 1.f;
            #pragma unroll
            for (int n = 0; n < 8; ++n) {
                const int gcol = wn * 128 + n * 16 + l16;
                const int h = gcol >> 5, dd = gcol & 31;
                vm[((size_t)(bb * NH + h) * NPIX + pix) * HD + dd] =
                    f2bf(mf * (acc[m][n][r] + bias[gcol]));
            }
        }
    }
}

// ---------------- Kernel 2: box+attn projection as tiled f32 GEMM (2400x256x256) --------
__global__ __launch_bounds__(256)
void proj_gemm(const float* __restrict__ query,
               const float* __restrict__ box_w, const float* __restrict__ box_b,
               const float* __restrict__ attn_w, const float* __restrict__ attn_b,
               float* __restrict__ bp, float* __restrict__ ap, float* __restrict__ awo)
{
    __shared__ float As[16][65];
    __shared__ float Bs[16][65];
    const int tid = threadIdx.x;
    const int tr = tid >> 4, tc = tid & 15;
    float acc[4][4] = {};
    const int row0 = blockIdx.x * 64, col0 = blockIdx.y * 64;
    for (int k0 = 0; k0 < D; k0 += 16) {
        #pragma unroll
        for (int i = 0; i < 4; ++i) {
            int idx = tid + i * 256;
            int r = idx >> 4, kk = idx & 15;
            int qrow = min(row0 + r, NQ - 1);
            As[kk][r] = query[(size_t)qrow * D + k0 + kk];
            int c256 = col0 + r;
            const float* src = (c256 < 128) ? (box_w + (size_t)c256 * D)
                                            : (attn_w + (size_t)(c256 - 128) * D);
            Bs[kk][r] = src[k0 + kk];
        }
        __syncthreads();
        #pragma unroll
        for (int kk = 0; kk < 16; ++kk) {
            float a[4], bv[4];
            #pragma unroll
            for (int i = 0; i < 4; ++i) a[i] = As[kk][tr * 4 + i];
            #pragma unroll
            for (int j = 0; j < 4; ++j) bv[j] = Bs[kk][tc * 4 + j];
            #pragma unroll
            for (int i = 0; i < 4; ++i)
                #pragma unroll
                for (int j = 0; j < 4; ++j)
                    acc[i][j] += a[i] * bv[j];
        }
        __syncthreads();
    }
    #pragma unroll
    for (int i = 0; i < 4; ++i) {
        int q = row0 + tr * 4 + i;
        if (q >= NQ) continue;
        #pragma unroll
        for (int j = 0; j < 4; ++j) {
            int col = col0 + tc * 4 + j;
            if (col < 128) {
                bp[(size_t)q * 128 + col] = acc[i][j] + box_b[col];
            } else {
                int rc = col - 128;
                float val = acc[i][j] + attn_b[rc];
                ap[(size_t)q * 128 + rc] = val;
                int h = rc >> 4, bx = (rc >> 2) & 3, rr = (rc >> 1) & 1, cc = rc & 1;
                float* awq = awo + (size_t)q * 512 + (size_t)(h * NB + bx) * 16;
                awq[(2 * rr + 0) * 4 + 2 * cc + 0] = val;
                awq[(2 * rr + 0) * 4 + 2 * cc + 1] = val;
                awq[(2 * rr + 1) * 4 + 2 * cc + 0] = val;
                awq[(2 * rr + 1) * 4 + 2 * cc + 1] = val;
            }
        }
    }
}

// ---------------- Kernel 3: 3-phase sampling ----------------
// P0: softmax (shfl-reduce, 128 lanes) + box geometry (32 lanes).
// P1: 512 points -> offsets/weights/softmax scalars in LDS (computed ONCE per point).
// P2: (h,dd) threads: 4 gathers + 6 FMA per point; LDS reads are broadcasts.
__global__ __launch_bounds__(256)
void sample_kernel(const unsigned short* __restrict__ vm, const float* __restrict__ bp,
                   const float* __restrict__ ap, const float* __restrict__ ref_windows,
                   const float* __restrict__ vratio, const int* __restrict__ vshape,
                   float* __restrict__ outp, float* __restrict__ moutp)
{
    __shared__ float sbp[128], sap[128], swh[128], lwh[128], sref4[4];
    __shared__ float4 boxdat[32];
    __shared__ int4   O4[512];
    __shared__ float4 W4[512];
    __shared__ float2 SL[512];
    const int blk = blockIdx.x, tid = threadIdx.x;
    const int bb = blk / NL;
    if (tid < 128) { sbp[tid] = bp[(size_t)blk * 128 + tid]; sap[tid] = ap[(size_t)blk * 128 + tid]; }
    if (tid < 4) sref4[tid] = ref_windows[(size_t)blk * 4 + tid];
    __syncthreads();
    const int Hf = vshape[0], Wf = vshape[1];
    const float Hff = (float)Hf, Wff = (float)Wf;
    const float vr0 = vratio[bb * 2 + 0], vr1 = vratio[bb * 2 + 1];

    if (tid < 128) {            // softmax over the 16 logits of head = tid>>4
        float a = sap[tid];     // lane k = box*4 + kpos (box bits [3:2], kpos bits [1:0])
        float m = a;
        m = fmaxf(m, __shfl_xor(m, 1));
        m = fmaxf(m, __shfl_xor(m, 2));
        m = fmaxf(m, __shfl_xor(m, 4));
        m = fmaxf(m, __shfl_xor(m, 8));
        float e = expf(a - m);
        float ldv = e + __shfl_xor(e, 4);   // sum over boxes
        ldv += __shfl_xor(ldv, 8);
        float ss = ldv + __shfl_xor(ldv, 1); // sum over kpos -> total
        ss += __shfl_xor(ss, 2);
        swh[tid] = e / (4.f * ss);           // spatial weight (64-wide softmax, 4x repeat)
        lwh[tid] = e / ldv;                  // level weight
    } else if (tid < 160) {     // box geometry: j = h*4+box
        int j = tid - 128;
        float o0 = sbp[j * 4 + 0], o1 = sbp[j * 4 + 1];
        float o2 = sbp[j * 4 + 2], o3 = sbp[j * 4 + 3];
        float cx = sref4[0] + o0 * 0.125f * sref4[2];
        float cy = sref4[1] + o1 * 0.125f * sref4[3];
        float rw = fmaxf(sref4[2] + o2 * 0.125f * sref4[2], 0.f);
        float rh = fmaxf(sref4[3] + o3 * 0.125f * sref4[3], 0.f);
        boxdat[j] = make_float4(cx, cy, rw, rh);
    }
    __syncthreads();

    const float kidx[4] = {-0.375f, -0.125f, 0.125f, 0.375f};
    #pragma unroll
    for (int pp = 0; pp < 2; ++pp) {        // p = h*64 + box*16 + ii*4 + jj
        const int p = tid + pp * 256;
        const float4 bd = boxdat[p >> 4];
        const int ii = (p >> 2) & 3, jj = p & 3;
        const float gy = (bd.y + kidx[ii] * bd.w) * vr1;
        const float gx = (bd.x + kidx[jj] * bd.z) * vr0;
        const float y = gy * Hff - 0.5f, x = gx * Wff - 0.5f;
        const float y0f = floorf(y), x0f = floorf(x);
        const int iy0 = (int)y0f, ix0 = (int)x0f;
        const float wy1 = y - y0f, wx1 = x - x0f;
        const float wy0 = 1.f - wy1, wx0 = 1.f - wx1;
        const bool y0in = (iy0 >= 0) & (iy0 < Hf);
        const bool y1in = (iy0 + 1 >= 0) & (iy0 + 1 < Hf);
        const bool x0in = (ix0 >= 0) & (ix0 < Wf);
        const bool x1in = (ix0 + 1 >= 0) & (ix0 + 1 < Wf);
        const int yc0 = min(max(iy0, 0), Hf - 1), yc1 = min(max(iy0 + 1, 0), Hf - 1);
        const int xc0 = min(max(ix0, 0), Wf - 1), xc1 = min(max(ix0 + 1, 0), Wf - 1);
        O4[p] = make_int4((yc0 * Wf + xc0) * HD, (yc0 * Wf + xc1) * HD,
                          (yc1 * Wf + xc0) * HD, (yc1 * Wf + xc1) * HD);
        W4[p] = make_float4((y0in & x0in) ? wy0 * wx0 : 0.f,
                            (y0in & x1in) ? wy0 * wx1 : 0.f,
                            (y1in & x0in) ? wy1 * wx0 : 0.f,
                            (y1in & x1in) ? wy1 * wx1 : 0.f);
        // kpos = (ii>>1)*2 + (jj>>1) = bit3(p)<<1 | bit1(p)
        const int kpos = ((p >> 2) & 2) | ((p >> 1) & 1);
        const int hk = (p >> 6) * 16 + ((p >> 4) & 3) * 4 + kpos;
        SL[p] = make_float2(swh[hk], lwh[hk]);
    }
    __syncthreads();

    const int h = tid >> 5, dd = tid & 31;
    const unsigned short* base = vm + ((size_t)(bb * NH + h) * NPIX) * HD + dd;
    float acc = 0.f, accm = 0.f;
    #pragma unroll 4
    for (int t = 0; t < 64; ++t) {
        const int p = h * 64 + t;
        const int4 o = O4[p]; const float4 w = W4[p]; const float2 sl = SL[p];
        const float samp = bf2f(base[o.x]) * w.x + bf2f(base[o.y]) * w.y
                         + bf2f(base[o.z]) * w.z + bf2f(base[o.w]) * w.w;
        acc  += samp * sl.x;
        accm += samp * sl.y;
    }
    outp[(size_t)blk * 256 + tid]  = acc;
    moutp[(size_t)blk * 256 + tid] = accm;
}

// ---------------- Kernel 4: output projection, bf16 MFMA, stacked A, IN-PLACE -----------
__global__ __launch_bounds__(512)
void oproj_mfma(const float* __restrict__ R, const float* __restrict__ W,
                const float* __restrict__ bias, float* __restrict__ Out)
{
    __shared__ short As[128][72];
    __shared__ short Bs[256][72];
    const int tid  = threadIdx.x;
    const int lane = tid & 63, wid = tid >> 6;      // 8 waves
    const int wm = wid >> 2, wn = wid & 3;          // 2x4 wave grid, 64x64 each
    const int row0 = blockIdx.x * 128;
    const int l16 = lane & 15, lg = lane >> 4;

    f32x4 acc[4][4] = {};
    const int arr = tid >> 2;            // 0..127
    const int ark = (tid & 3) * 16;      // 0/16/32/48
    const int brr = tid >> 1;            // 0..255
    const int brk = (tid & 1) * 32;      // 0/32

    for (int k0 = 0; k0 < D; k0 += 64) {
        const int arow = min(row0 + arr, NR - 1);
        const f32x4* pa = (const f32x4*)(R + (size_t)arow * D + k0 + ark);
        #pragma unroll
        for (int j = 0; j < 2; ++j)
            *(bf16x8*)&As[arr][ark + j * 8] = pack8(pa[2 * j], pa[2 * j + 1]);
        const f32x4* pb = (const f32x4*)(W + (size_t)brr * D + k0 + brk);
        #pragma unroll
        for (int j = 0; j < 4; ++j)
            *(bf16x8*)&Bs[brr][brk + j * 8] = pack8(pb[2 * j], pb[2 * j + 1]);
        __syncthreads();
        #pragma unroll
        for (int kk = 0; kk < 2; ++kk) {
            bf16x8 af[4], bfr[4];
            #pragma unroll
            for (int m = 0; m < 4; ++m)
                af[m] = *(const bf16x8*)&As[wm * 64 + m * 16 + l16][kk * 32 + lg * 8];
            #pragma unroll
            for (int n = 0; n < 4; ++n)
                bfr[n] = *(const bf16x8*)&Bs[wn * 64 + n * 16 + l16][kk * 32 + lg * 8];
            #pragma unroll
            for (int m = 0; m < 4; ++m)
                #pragma unroll
                for (int n = 0; n < 4; ++n)
                    acc[m][n] = __builtin_amdgcn_mfma_f32_16x16x32_bf16(af[m], bfr[n], acc[m][n], 0, 0, 0);
        }
        __syncthreads();
    }
    #pragma unroll
    for (int m = 0; m < 4; ++m) {
        #pragma unroll
        for (int r = 0; r < 4; ++r) {
            const int grow = row0 + wm * 64 + m * 16 + lg * 4 + r;
            if (grow >= NR) continue;
            #pragma unroll
            for (int n = 0; n < 4; ++n) {
                const int gcol = wn * 64 + n * 16 + l16;
                Out[(size_t)grow * D + gcol] = acc[m][n][r] + bias[gcol];
            }
        }
    }
}

extern "C" void kernel_launch(void* const* d_in, const int* in_sizes, int n_in,
                              void* d_out, int out_size, void* d_ws, size_t ws_size,
                              hipStream_t stream)
{
    const float* query        = (const float*)d_in[0];
    const float* value        = (const float*)d_in[1];
    const int*   vshape       = (const int*)d_in[2];
    const unsigned char* vmask= (const unsigned char*)d_in[3];
    const float* vratio       = (const float*)d_in[5];
    const float* refw         = (const float*)d_in[6];
    const float* box_w        = (const float*)d_in[7];
    const float* box_b        = (const float*)d_in[8];
    const float* attn_w       = (const float*)d_in[9];
    const float* attn_b       = (const float*)d_in[10];
    const float* vproj_w      = (const float*)d_in[11];
    const float* vproj_b      = (const float*)d_in[12];
    const float* oproj_w      = (const float*)d_in[13];
    const float* oproj_b      = (const float*)d_in[14];

    unsigned short* vm_b  = (unsigned short*)d_ws;     // 8,388,608 bf16 (16.8 MB)
    unsigned short* val_b = vm_b + 8388608;            // 8,388,608 bf16
    unsigned short* w_b   = val_b + 8388608;           // 65,536 bf16
    float* bp = (float*)(w_b + 65536);                 // 307,200 f32 (16B-aligned)
    float* ap = bp + 307200;                           // 307,200 f32
    // total ws: 36.1 MB

    float* out1 = (float*)d_out;          // output       614,400
    float* out2 = out1 + 614400;          // mask_output  614,400
    float* awo  = out2 + 614400;          // aw repeated  1,228,800

    float* outp  = out1;                  // pre-projection accumulators (in-place oproj)
    float* moutp = out2;

    tobf16_kernel<<<4096, 256, 0, stream>>>(value, vproj_w, val_b, w_b);
    vproj_mfma<<<512, 256, 0, stream>>>(val_b, w_b, vproj_b, vmask, vm_b);
    proj_gemm<<<dim3(38, 4), 256, 0, stream>>>(query, box_w, box_b, attn_w, attn_b, bp, ap, awo);
    sample_kernel<<<NQ, 256, 0, stream>>>(vm_b, bp, ap, refw, vratio, vshape, outp, moutp);
    oproj_mfma<<<38, 512, 0, stream>>>(out1, oproj_w, oproj_b, out1);
}

// Round 8
// 206.672 us; speedup vs baseline: 1.9102x; 1.0449x over previous
//
#include <hip/hip_runtime.h>
#include <cstddef>

#define NH   8
#define NB   4
#define HD   32
#define NPIX 4096
#define NBATCH 8
#define NL   300
#define D    256
#define NQ   (NBATCH * NL)          // 2400
#define NR   (2 * NQ)               // 4800 stacked rows for oproj

typedef __attribute__((ext_vector_type(4))) float  f32x4;
typedef __attribute__((ext_vector_type(8))) short  bf16x8;

__device__ __forceinline__ unsigned short f2bf(float f) {
    union { float f; unsigned u; } v; v.f = f;
    unsigned r = v.u + 0x7fffu + ((v.u >> 16) & 1u);   // round-to-nearest-even
    return (unsigned short)(r >> 16);
}
__device__ __forceinline__ float bf2f(unsigned short u) {
    union { unsigned u; float f; } v; v.u = ((unsigned)u) << 16; return v.f;
}
// HW packed f32->bf16 (RNE), 1 instr per 2 floats (T12 recipe; no builtin on gfx950)
__device__ __forceinline__ unsigned cvtpk(float lo, float hi) {
    unsigned r;
    asm("v_cvt_pk_bf16_f32 %0, %1, %2" : "=v"(r) : "v"(lo), "v"(hi));
    return r;
}
__device__ __forceinline__ bf16x8 pack8c(f32x4 a, f32x4 b) {
    union { unsigned u[4]; bf16x8 v; } r;
    r.u[0] = cvtpk(a[0], a[1]); r.u[1] = cvtpk(a[2], a[3]);
    r.u[2] = cvtpk(b[0], b[1]); r.u[3] = cvtpk(b[2], b[3]);
    return r.v;
}

// ---------------- Kernel 0: weights f32 -> bf16 (vproj_w, oproj_w; 64 blocks) ----------
__global__ __launch_bounds__(256)
void tow_kernel(const float* __restrict__ vproj_w, const float* __restrict__ oproj_w,
                unsigned short* __restrict__ wv, unsigned short* __restrict__ wo)
{
    const int i = blockIdx.x * 256 + threadIdx.x;    // 16384 threads, 8 elems each
    const float* src = (i < 8192) ? vproj_w : oproj_w;
    unsigned short* dst = (i < 8192) ? wv : wo;
    const size_t off = (size_t)(i & 8191) * 8;
    f32x4 a = *(const f32x4*)(src + off);
    f32x4 b = *(const f32x4*)(src + off + 4);
    *(bf16x8*)(dst + off) = pack8c(a, b);
}

// ---------------- Kernel 1 (FAT): vproj direct-MFMA (blocks 0..511)  ||
//                                  box/attn f32 GEMM  (blocks 512..663) ----------------
__global__ __launch_bounds__(256)
void fat_kernel(const float* __restrict__ value, const unsigned short* __restrict__ Wv,
                const float* __restrict__ vbias, const unsigned char* __restrict__ mask,
                unsigned short* __restrict__ vm,
                const float* __restrict__ query,
                const float* __restrict__ box_w, const float* __restrict__ box_b,
                const float* __restrict__ attn_w, const float* __restrict__ attn_b,
                float* __restrict__ bp, float* __restrict__ ap, float* __restrict__ awo)
{
    __shared__ float As[16][65];
    __shared__ float Bs[16][65];
    const int bid = blockIdx.x;
    const int tid = threadIdx.x;

    if (bid < 512) {
        // ---- vproj: M=32768(value rows) x N=256 x K=256, A f32 converted in-reg ----
        const int lane = tid & 63, wid = tid >> 6;
        const int wm = wid >> 1, wn = wid & 1;       // wave tile 32(M) x 128(N)
        const int row0 = bid * 64;
        const int l16 = lane & 15, lg = lane >> 4;

        f32x4 acc[2][8] = {};
        const float*          pa0 = value + (size_t)(row0 + wm * 32 + l16) * D + lg * 8;
        const unsigned short* pb0 = Wv    + (size_t)(wn * 128 + l16) * D + lg * 8;

        #pragma unroll
        for (int ks = 0; ks < 8; ++ks) {
            bf16x8 af[2], bfr[8];
            #pragma unroll
            for (int m = 0; m < 2; ++m) {
                const float* pa = pa0 + (size_t)m * 16 * D + ks * 32;
                af[m] = pack8c(*(const f32x4*)pa, *(const f32x4*)(pa + 4));
            }
            #pragma unroll
            for (int n = 0; n < 8; ++n)
                bfr[n] = *(const bf16x8*)(pb0 + (size_t)n * 16 * D + ks * 32);
            #pragma unroll
            for (int m = 0; m < 2; ++m)
                #pragma unroll
                for (int n = 0; n < 8; ++n)
                    acc[m][n] = __builtin_amdgcn_mfma_f32_16x16x32_bf16(af[m], bfr[n], acc[m][n], 0, 0, 0);
        }
        // C/D layout: col = lane&15, row = (lane>>4)*4 + reg
        #pragma unroll
        for (int m = 0; m < 2; ++m) {
            #pragma unroll
            for (int r = 0; r < 4; ++r) {
                const int grow = row0 + wm * 32 + m * 16 + lg * 4 + r;
                const int bb = grow >> 12, pix = grow & (NPIX - 1);
                const float mf = (mask[grow] != 0) ? 0.f : 1.f;
                #pragma unroll
                for (int n = 0; n < 8; ++n) {
                    const int gcol = wn * 128 + n * 16 + l16;
                    const int h = gcol >> 5, dd = gcol & 31;
                    vm[((size_t)(bb * NH + h) * NPIX + pix) * HD + dd] =
                        f2bf(mf * (acc[m][n][r] + vbias[gcol]));
                }
            }
        }
    } else {
        // ---- proj: f32 tiled GEMM, 2400 x 256(box128|attn128) x 256 ----
        const int pid = bid - 512;                   // 0..151 -> (38, 4)
        const int row0 = (pid % 38) * 64, col0 = (pid / 38) * 64;
        const int tr = tid >> 4, tc = tid & 15;
        float acc[4][4] = {};
        for (int k0 = 0; k0 < D; k0 += 16) {
            #pragma unroll
            for (int i = 0; i < 4; ++i) {
                int idx = tid + i * 256;
                int r = idx >> 4, kk = idx & 15;
                int qrow = min(row0 + r, NQ - 1);
                As[kk][r] = query[(size_t)qrow * D + k0 + kk];
                int c256 = col0 + r;
                const float* src = (c256 < 128) ? (box_w + (size_t)c256 * D)
                                                : (attn_w + (size_t)(c256 - 128) * D);
                Bs[kk][r] = src[k0 + kk];
            }
            __syncthreads();
            #pragma unroll
            for (int kk = 0; kk < 16; ++kk) {
                float a[4], bv[4];
                #pragma unroll
                for (int i = 0; i < 4; ++i) a[i] = As[kk][tr * 4 + i];
                #pragma unroll
                for (int j = 0; j < 4; ++j) bv[j] = Bs[kk][tc * 4 + j];
                #pragma unroll
                for (int i = 0; i < 4; ++i)
                    #pragma unroll
                    for (int j = 0; j < 4; ++j)
                        acc[i][j] += a[i] * bv[j];
            }
            __syncthreads();
        }
        #pragma unroll
        for (int i = 0; i < 4; ++i) {
            int q = row0 + tr * 4 + i;
            if (q >= NQ) continue;
            #pragma unroll
            for (int j = 0; j < 4; ++j) {
                int col = col0 + tc * 4 + j;
                if (col < 128) {
                    bp[(size_t)q * 128 + col] = acc[i][j] + box_b[col];
                } else {
                    int rc = col - 128;
                    float val = acc[i][j] + attn_b[rc];
                    ap[(size_t)q * 128 + rc] = val;
                    int h = rc >> 4, bx = (rc >> 2) & 3, rr = (rc >> 1) & 1, cc = rc & 1;
                    float* awq = awo + (size_t)q * 512 + (size_t)(h * NB + bx) * 16;
                    awq[(2 * rr + 0) * 4 + 2 * cc + 0] = val;
                    awq[(2 * rr + 0) * 4 + 2 * cc + 1] = val;
                    awq[(2 * rr + 1) * 4 + 2 * cc + 0] = val;
                    awq[(2 * rr + 1) * 4 + 2 * cc + 1] = val;
                }
            }
        }
    }
}

// ---------------- Kernel 2: 3-phase sampling (unchanged from passing round 6) ----------
__global__ __launch_bounds__(256)
void sample_kernel(const unsigned short* __restrict__ vm, const float* __restrict__ bp,
                   const float* __restrict__ ap, const float* __restrict__ ref_windows,
                   const float* __restrict__ vratio, const int* __restrict__ vshape,
                   float* __restrict__ outp, float* __restrict__ moutp)
{
    __shared__ float sbp[128], sap[128], swh[128], lwh[128], sref4[4];
    __shared__ float4 boxdat[32];
    __shared__ int4   O4[512];
    __shared__ float4 W4[512];
    __shared__ float2 SL[512];
    const int blk = blockIdx.x, tid = threadIdx.x;
    const int bb = blk / NL;
    if (tid < 128) { sbp[tid] = bp[(size_t)blk * 128 + tid]; sap[tid] = ap[(size_t)blk * 128 + tid]; }
    if (tid < 4) sref4[tid] = ref_windows[(size_t)blk * 4 + tid];
    __syncthreads();
    const int Hf = vshape[0], Wf = vshape[1];
    const float Hff = (float)Hf, Wff = (float)Wf;
    const float vr0 = vratio[bb * 2 + 0], vr1 = vratio[bb * 2 + 1];

    if (tid < 128) {            // softmax over the 16 logits of head = tid>>4
        float a = sap[tid];     // lane k = box*4 + kpos
        float m = a;
        m = fmaxf(m, __shfl_xor(m, 1));
        m = fmaxf(m, __shfl_xor(m, 2));
        m = fmaxf(m, __shfl_xor(m, 4));
        m = fmaxf(m, __shfl_xor(m, 8));
        float e = expf(a - m);
        float ldv = e + __shfl_xor(e, 4);    // sum over boxes
        ldv += __shfl_xor(ldv, 8);
        float ss = ldv + __shfl_xor(ldv, 1); // sum over kpos -> total
        ss += __shfl_xor(ss, 2);
        swh[tid] = e / (4.f * ss);           // spatial weight
        lwh[tid] = e / ldv;                  // level weight
    } else if (tid < 160) {     // box geometry: j = h*4+box
        int j = tid - 128;
        float o0 = sbp[j * 4 + 0], o1 = sbp[j * 4 + 1];
        float o2 = sbp[j * 4 + 2], o3 = sbp[j * 4 + 3];
        float cx = sref4[0] + o0 * 0.125f * sref4[2];
        float cy = sref4[1] + o1 * 0.125f * sref4[3];
        float rw = fmaxf(sref4[2] + o2 * 0.125f * sref4[2], 0.f);
        float rh = fmaxf(sref4[3] + o3 * 0.125f * sref4[3], 0.f);
        boxdat[j] = make_float4(cx, cy, rw, rh);
    }
    __syncthreads();

    const float kidx[4] = {-0.375f, -0.125f, 0.125f, 0.375f};
    #pragma unroll
    for (int pp = 0; pp < 2; ++pp) {        // p = h*64 + box*16 + ii*4 + jj
        const int p = tid + pp * 256;
        const float4 bd = boxdat[p >> 4];
        const int ii = (p >> 2) & 3, jj = p & 3;
        const float gy = (bd.y + kidx[ii] * bd.w) * vr1;
        const float gx = (bd.x + kidx[jj] * bd.z) * vr0;
        const float y = gy * Hff - 0.5f, x = gx * Wff - 0.5f;
        const float y0f = floorf(y), x0f = floorf(x);
        const int iy0 = (int)y0f, ix0 = (int)x0f;
        const float wy1 = y - y0f, wx1 = x - x0f;
        const float wy0 = 1.f - wy1, wx0 = 1.f - wx1;
        const bool y0in = (iy0 >= 0) & (iy0 < Hf);
        const bool y1in = (iy0 + 1 >= 0) & (iy0 + 1 < Hf);
        const bool x0in = (ix0 >= 0) & (ix0 < Wf);
        const bool x1in = (ix0 + 1 >= 0) & (ix0 + 1 < Wf);
        const int yc0 = min(max(iy0, 0), Hf - 1), yc1 = min(max(iy0 + 1, 0), Hf - 1);
        const int xc0 = min(max(ix0, 0), Wf - 1), xc1 = min(max(ix0 + 1, 0), Wf - 1);
        O4[p] = make_int4((yc0 * Wf + xc0) * HD, (yc0 * Wf + xc1) * HD,
                          (yc1 * Wf + xc0) * HD, (yc1 * Wf + xc1) * HD);
        W4[p] = make_float4((y0in & x0in) ? wy0 * wx0 : 0.f,
                            (y0in & x1in) ? wy0 * wx1 : 0.f,
                            (y1in & x0in) ? wy1 * wx0 : 0.f,
                            (y1in & x1in) ? wy1 * wx1 : 0.f);
        // kpos = (ii>>1)*2 + (jj>>1) = bit3(p)<<1 | bit1(p)
        const int kpos = ((p >> 2) & 2) | ((p >> 1) & 1);
        const int hk = (p >> 6) * 16 + ((p >> 4) & 3) * 4 + kpos;
        SL[p] = make_float2(swh[hk], lwh[hk]);
    }
    __syncthreads();

    const int h = tid >> 5, dd = tid & 31;
    const unsigned short* base = vm + ((size_t)(bb * NH + h) * NPIX) * HD + dd;
    float acc = 0.f, accm = 0.f;
    #pragma unroll 4
    for (int t = 0; t < 64; ++t) {
        const int p = h * 64 + t;
        const int4 o = O4[p]; const float4 w = W4[p]; const float2 sl = SL[p];
        const float samp = bf2f(base[o.x]) * w.x + bf2f(base[o.y]) * w.y
                         + bf2f(base[o.z]) * w.z + bf2f(base[o.w]) * w.w;
        acc  += samp * sl.x;
        accm += samp * sl.y;
    }
    outp[(size_t)blk * 256 + tid]  = acc;
    moutp[(size_t)blk * 256 + tid] = accm;
}

// ---------------- Kernel 3: oproj direct-MFMA, 64-row tiles, IN-PLACE -------------------
// Block reads ONLY rows [row0,row0+64) (A rows == C rows, weights separate) -> no
// cross-block hazard; within block all reads precede epilogue writes.
__global__ __launch_bounds__(256)
void oproj_direct(const float* __restrict__ R, const unsigned short* __restrict__ Wo,
                  const float* __restrict__ bias, float* __restrict__ Out)
{
    const int tid  = threadIdx.x;
    const int lane = tid & 63, wid = tid >> 6;
    const int wm = wid >> 1, wn = wid & 1;           // wave tile 32(M) x 128(N)
    const int row0 = blockIdx.x * 64;                // 75 blocks * 64 = 4800 exact
    const int l16 = lane & 15, lg = lane >> 4;

    f32x4 acc[2][8] = {};
    const float*          pa0 = R  + (size_t)(row0 + wm * 32 + l16) * D + lg * 8;
    const unsigned short* pb0 = Wo + (size_t)(wn * 128 + l16) * D + lg * 8;

    #pragma unroll
    for (int ks = 0; ks < 8; ++ks) {
        bf16x8 af[2], bfr[8];
        #pragma unroll
        for (int m = 0; m < 2; ++m) {
            const float* pa = pa0 + (size_t)m * 16 * D + ks * 32;
            af[m] = pack8c(*(const f32x4*)pa, *(const f32x4*)(pa + 4));
        }
        #pragma unroll
        for (int n = 0; n < 8; ++n)
            bfr[n] = *(const bf16x8*)(pb0 + (size_t)n * 16 * D + ks * 32);
        #pragma unroll
        for (int m = 0; m < 2; ++m)
            #pragma unroll
            for (int n = 0; n < 8; ++n)
                acc[m][n] = __builtin_amdgcn_mfma_f32_16x16x32_bf16(af[m], bfr[n], acc[m][n], 0, 0, 0);
    }
    #pragma unroll
    for (int m = 0; m < 2; ++m) {
        #pragma unroll
        for (int r = 0; r < 4; ++r) {
            const int grow = row0 + wm * 32 + m * 16 + lg * 4 + r;
            #pragma unroll
            for (int n = 0; n < 8; ++n) {
                const int gcol = wn * 128 + n * 16 + l16;
                Out[(size_t)grow * D + gcol] = acc[m][n][r] + bias[gcol];
            }
        }
    }
}

extern "C" void kernel_launch(void* const* d_in, const int* in_sizes, int n_in,
                              void* d_out, int out_size, void* d_ws, size_t ws_size,
                              hipStream_t stream)
{
    const float* query        = (const float*)d_in[0];
    const float* value        = (const float*)d_in[1];
    const int*   vshape       = (const int*)d_in[2];
    const unsigned char* vmask= (const unsigned char*)d_in[3];
    const float* vratio       = (const float*)d_in[5];
    const float* refw         = (const float*)d_in[6];
    const float* box_w        = (const float*)d_in[7];
    const float* box_b        = (const float*)d_in[8];
    const float* attn_w       = (const float*)d_in[9];
    const float* attn_b       = (const float*)d_in[10];
    const float* vproj_w      = (const float*)d_in[11];
    const float* vproj_b      = (const float*)d_in[12];
    const float* oproj_w      = (const float*)d_in[13];
    const float* oproj_b      = (const float*)d_in[14];

    unsigned short* vm_b = (unsigned short*)d_ws;      // 8,388,608 bf16 (16.8 MB)
    unsigned short* wv   = vm_b + 8388608;             // 65,536 bf16
    unsigned short* wo   = wv + 65536;                 // 65,536 bf16
    float* bp = (float*)(wo + 65536);                  // 307,200 f32
    float* ap = bp + 307200;                           // 307,200 f32
    // total ws ~19.5 MB

    float* out1 = (float*)d_out;          // output       614,400
    float* out2 = out1 + 614400;          // mask_output  614,400
    float* awo  = out2 + 614400;          // aw repeated  1,228,800

    float* outp  = out1;                  // pre-projection accumulators (in-place oproj)
    float* moutp = out2;

    tow_kernel<<<64, 256, 0, stream>>>(vproj_w, oproj_w, wv, wo);
    fat_kernel<<<664, 256, 0, stream>>>(value, wv, vproj_b, vmask, vm_b,
                                        query, box_w, box_b, attn_w, attn_b, bp, ap, awo);
    sample_kernel<<<NQ, 256, 0, stream>>>(vm_b, bp, ap, refw, vratio, vshape, outp, moutp);
    oproj_direct<<<75, 256, 0, stream>>>(out1, wo, oproj_b, out1);
}

// Round 9
// 198.024 us; speedup vs baseline: 1.9936x; 1.0437x over previous
//
#include <hip/hip_runtime.h>
#include <cstddef>

#define NH   8
#define NB   4
#define HD   32
#define NPIX 4096
#define NBATCH 8
#define NL   300
#define D    256
#define NQ   (NBATCH * NL)          // 2400
#define NR   (2 * NQ)               // 4800 stacked rows for oproj

typedef __attribute__((ext_vector_type(4))) float  f32x4;
typedef __attribute__((ext_vector_type(8))) short  bf16x8;

__device__ __forceinline__ unsigned short f2bf(float f) {
    union { float f; unsigned u; } v; v.f = f;
    unsigned r = v.u + 0x7fffu + ((v.u >> 16) & 1u);   // round-to-nearest-even
    return (unsigned short)(r >> 16);
}
__device__ __forceinline__ float bf2f(unsigned short u) {
    union { unsigned u; float f; } v; v.u = ((unsigned)u) << 16; return v.f;
}
// HW packed f32->bf16 (RNE), 1 instr per 2 floats
__device__ __forceinline__ unsigned cvtpk(float lo, float hi) {
    unsigned r;
    asm("v_cvt_pk_bf16_f32 %0, %1, %2" : "=v"(r) : "v"(lo), "v"(hi));
    return r;
}
__device__ __forceinline__ bf16x8 pack8c(f32x4 a, f32x4 b) {
    union { unsigned u[4]; bf16x8 v; } r;
    r.u[0] = cvtpk(a[0], a[1]); r.u[1] = cvtpk(a[2], a[3]);
    r.u[2] = cvtpk(b[0], b[1]); r.u[3] = cvtpk(b[2], b[3]);
    return r.v;
}

// ---------------- Kernel 1 (FAT): vproj LDS-staged MFMA (blocks 0..511) ||
//                                  box/attn f32 GEMM     (blocks 512..663) --------------
// vproj: M=32768 x N=256 x K=256, tiles BM=128/BN=128/BK=64. Coalesced f32 loads,
// in-reg cvt_pk to bf16, padded LDS [.][72] (2-way read conflict = free), 4 waves.
__global__ __launch_bounds__(256)
void fat_kernel(const float* __restrict__ value, const float* __restrict__ Wvf,
                const float* __restrict__ vbias, const unsigned char* __restrict__ mask,
                unsigned short* __restrict__ vm,
                const float* __restrict__ query,
                const float* __restrict__ box_w, const float* __restrict__ box_b,
                const float* __restrict__ attn_w, const float* __restrict__ attn_b,
                float* __restrict__ bp, float* __restrict__ ap, float* __restrict__ awo)
{
    __shared__ __align__(16) short As[128][72];
    __shared__ __align__(16) short Bs[128][72];
    const int bid = blockIdx.x;
    const int tid = threadIdx.x;

    if (bid < 512) {
        const int mt = bid >> 1, nt = bid & 1;
        const int row0 = mt * 128, col0 = nt * 128;
        const int lane = tid & 63, wid = tid >> 6;
        const int wm = wid >> 1, wn = wid & 1;       // 2x2 wave grid, 64x64 wave tile
        const int l16 = lane & 15, lg = lane >> 4;

        f32x4 acc[4][4] = {};
        for (int k0 = 0; k0 < D; k0 += 64) {
            // stage A (value f32 -> bf16) and B (vproj_w f32 -> bf16), coalesced
            #pragma unroll
            for (int i = 0; i < 4; ++i) {
                const int t = tid + i * 256;
                const int r = t >> 3, c8 = (t & 7) * 8;
                const float* p = value + (size_t)(row0 + r) * D + k0 + c8;
                *(bf16x8*)&As[r][c8] = pack8c(*(const f32x4*)p, *(const f32x4*)(p + 4));
                const float* q = Wvf + (size_t)(col0 + r) * D + k0 + c8;
                *(bf16x8*)&Bs[r][c8] = pack8c(*(const f32x4*)q, *(const f32x4*)(q + 4));
            }
            __syncthreads();
            #pragma unroll
            for (int kk = 0; kk < 2; ++kk) {
                bf16x8 af[4], bfr[4];
                #pragma unroll
                for (int m = 0; m < 4; ++m)
                    af[m] = *(const bf16x8*)&As[wm * 64 + m * 16 + l16][kk * 32 + lg * 8];
                #pragma unroll
                for (int n = 0; n < 4; ++n)
                    bfr[n] = *(const bf16x8*)&Bs[wn * 64 + n * 16 + l16][kk * 32 + lg * 8];
                #pragma unroll
                for (int m = 0; m < 4; ++m)
                    #pragma unroll
                    for (int n = 0; n < 4; ++n)
                        acc[m][n] = __builtin_amdgcn_mfma_f32_16x16x32_bf16(af[m], bfr[n], acc[m][n], 0, 0, 0);
            }
            __syncthreads();
        }
        // epilogue: C/D layout col=lane&15, row=(lane>>4)*4+reg
        #pragma unroll
        for (int m = 0; m < 4; ++m) {
            #pragma unroll
            for (int r = 0; r < 4; ++r) {
                const int grow = row0 + wm * 64 + m * 16 + lg * 4 + r;
                const int bb = grow >> 12, pix = grow & (NPIX - 1);
                const float mf = (mask[grow] != 0) ? 0.f : 1.f;
                #pragma unroll
                for (int n = 0; n < 4; ++n) {
                    const int gcol = col0 + wn * 64 + n * 16 + l16;
                    const int h = gcol >> 5, dd = gcol & 31;
                    vm[((size_t)(bb * NH + h) * NPIX + pix) * HD + dd] =
                        f2bf(mf * (acc[m][n][r] + vbias[gcol]));
                }
            }
        }
    } else {
        // ---- proj: f32 tiled GEMM, 2400 x 256(box128|attn128) x 256 ----
        float (*Asf)[65] = (float (*)[65])&As[0][0];   // reuse LDS (4160B each, fits)
        float (*Bsf)[65] = (float (*)[65])&Bs[0][0];
        const int pid = bid - 512;                   // 0..151 -> (38, 4)
        const int row0 = (pid % 38) * 64, col0 = (pid / 38) * 64;
        const int tr = tid >> 4, tc = tid & 15;
        float acc[4][4] = {};
        for (int k0 = 0; k0 < D; k0 += 16) {
            #pragma unroll
            for (int i = 0; i < 4; ++i) {
                int idx = tid + i * 256;
                int r = idx >> 4, kk = idx & 15;
                int qrow = min(row0 + r, NQ - 1);
                Asf[kk][r] = query[(size_t)qrow * D + k0 + kk];
                int c256 = col0 + r;
                const float* src = (c256 < 128) ? (box_w + (size_t)c256 * D)
                                                : (attn_w + (size_t)(c256 - 128) * D);
                Bsf[kk][r] = src[k0 + kk];
            }
            __syncthreads();
            #pragma unroll
            for (int kk = 0; kk < 16; ++kk) {
                float a[4], bv[4];
                #pragma unroll
                for (int i = 0; i < 4; ++i) a[i] = Asf[kk][tr * 4 + i];
                #pragma unroll
                for (int j = 0; j < 4; ++j) bv[j] = Bsf[kk][tc * 4 + j];
                #pragma unroll
                for (int i = 0; i < 4; ++i)
                    #pragma unroll
                    for (int j = 0; j < 4; ++j)
                        acc[i][j] += a[i] * bv[j];
            }
            __syncthreads();
        }
        #pragma unroll
        for (int i = 0; i < 4; ++i) {
            int q = row0 + tr * 4 + i;
            if (q >= NQ) continue;
            #pragma unroll
            for (int j = 0; j < 4; ++j) {
                int col = col0 + tc * 4 + j;
                if (col < 128) {
                    bp[(size_t)q * 128 + col] = acc[i][j] + box_b[col];
                } else {
                    int rc = col - 128;
                    float val = acc[i][j] + attn_b[rc];
                    ap[(size_t)q * 128 + rc] = val;
                    int h = rc >> 4, bx = (rc >> 2) & 3, rr = (rc >> 1) & 1, cc = rc & 1;
                    float* awq = awo + (size_t)q * 512 + (size_t)(h * NB + bx) * 16;
                    awq[(2 * rr + 0) * 4 + 2 * cc + 0] = val;
                    awq[(2 * rr + 0) * 4 + 2 * cc + 1] = val;
                    awq[(2 * rr + 1) * 4 + 2 * cc + 0] = val;
                    awq[(2 * rr + 1) * 4 + 2 * cc + 1] = val;
                }
            }
        }
    }
}

// ---------------- Kernel 2: 3-phase sampling (unchanged, passing) ----------------------
__global__ __launch_bounds__(256)
void sample_kernel(const unsigned short* __restrict__ vm, const float* __restrict__ bp,
                   const float* __restrict__ ap, const float* __restrict__ ref_windows,
                   const float* __restrict__ vratio, const int* __restrict__ vshape,
                   float* __restrict__ outp, float* __restrict__ moutp)
{
    __shared__ float sbp[128], sap[128], swh[128], lwh[128], sref4[4];
    __shared__ float4 boxdat[32];
    __shared__ int4   O4[512];
    __shared__ float4 W4[512];
    __shared__ float2 SL[512];
    const int blk = blockIdx.x, tid = threadIdx.x;
    const int bb = blk / NL;
    if (tid < 128) { sbp[tid] = bp[(size_t)blk * 128 + tid]; sap[tid] = ap[(size_t)blk * 128 + tid]; }
    if (tid < 4) sref4[tid] = ref_windows[(size_t)blk * 4 + tid];
    __syncthreads();
    const int Hf = vshape[0], Wf = vshape[1];
    const float Hff = (float)Hf, Wff = (float)Wf;
    const float vr0 = vratio[bb * 2 + 0], vr1 = vratio[bb * 2 + 1];

    if (tid < 128) {            // softmax over the 16 logits of head = tid>>4
        float a = sap[tid];     // lane k = box*4 + kpos
        float m = a;
        m = fmaxf(m, __shfl_xor(m, 1));
        m = fmaxf(m, __shfl_xor(m, 2));
        m = fmaxf(m, __shfl_xor(m, 4));
        m = fmaxf(m, __shfl_xor(m, 8));
        float e = expf(a - m);
        float ldv = e + __shfl_xor(e, 4);    // sum over boxes
        ldv += __shfl_xor(ldv, 8);
        float ss = ldv + __shfl_xor(ldv, 1); // sum over kpos -> total
        ss += __shfl_xor(ss, 2);
        swh[tid] = e / (4.f * ss);           // spatial weight
        lwh[tid] = e / ldv;                  // level weight
    } else if (tid < 160) {     // box geometry: j = h*4+box
        int j = tid - 128;
        float o0 = sbp[j * 4 + 0], o1 = sbp[j * 4 + 1];
        float o2 = sbp[j * 4 + 2], o3 = sbp[j * 4 + 3];
        float cx = sref4[0] + o0 * 0.125f * sref4[2];
        float cy = sref4[1] + o1 * 0.125f * sref4[3];
        float rw = fmaxf(sref4[2] + o2 * 0.125f * sref4[2], 0.f);
        float rh = fmaxf(sref4[3] + o3 * 0.125f * sref4[3], 0.f);
        boxdat[j] = make_float4(cx, cy, rw, rh);
    }
    __syncthreads();

    const float kidx[4] = {-0.375f, -0.125f, 0.125f, 0.375f};
    #pragma unroll
    for (int pp = 0; pp < 2; ++pp) {        // p = h*64 + box*16 + ii*4 + jj
        const int p = tid + pp * 256;
        const float4 bd = boxdat[p >> 4];
        const int ii = (p >> 2) & 3, jj = p & 3;
        const float gy = (bd.y + kidx[ii] * bd.w) * vr1;
        const float gx = (bd.x + kidx[jj] * bd.z) * vr0;
        const float y = gy * Hff - 0.5f, x = gx * Wff - 0.5f;
        const float y0f = floorf(y), x0f = floorf(x);
        const int iy0 = (int)y0f, ix0 = (int)x0f;
        const float wy1 = y - y0f, wx1 = x - x0f;
        const float wy0 = 1.f - wy1, wx0 = 1.f - wx1;
        const bool y0in = (iy0 >= 0) & (iy0 < Hf);
        const bool y1in = (iy0 + 1 >= 0) & (iy0 + 1 < Hf);
        const bool x0in = (ix0 >= 0) & (ix0 < Wf);
        const bool x1in = (ix0 + 1 >= 0) & (ix0 + 1 < Wf);
        const int yc0 = min(max(iy0, 0), Hf - 1), yc1 = min(max(iy0 + 1, 0), Hf - 1);
        const int xc0 = min(max(ix0, 0), Wf - 1), xc1 = min(max(ix0 + 1, 0), Wf - 1);
        O4[p] = make_int4((yc0 * Wf + xc0) * HD, (yc0 * Wf + xc1) * HD,
                          (yc1 * Wf + xc0) * HD, (yc1 * Wf + xc1) * HD);
        W4[p] = make_float4((y0in & x0in) ? wy0 * wx0 : 0.f,
                            (y0in & x1in) ? wy0 * wx1 : 0.f,
                            (y1in & x0in) ? wy1 * wx0 : 0.f,
                            (y1in & x1in) ? wy1 * wx1 : 0.f);
        // kpos = (ii>>1)*2 + (jj>>1) = bit3(p)<<1 | bit1(p)
        const int kpos = ((p >> 2) & 2) | ((p >> 1) & 1);
        const int hk = (p >> 6) * 16 + ((p >> 4) & 3) * 4 + kpos;
        SL[p] = make_float2(swh[hk], lwh[hk]);
    }
    __syncthreads();

    const int h = tid >> 5, dd = tid & 31;
    const unsigned short* base = vm + ((size_t)(bb * NH + h) * NPIX) * HD + dd;
    float acc = 0.f, accm = 0.f;
    #pragma unroll 4
    for (int t = 0; t < 64; ++t) {
        const int p = h * 64 + t;
        const int4 o = O4[p]; const float4 w = W4[p]; const float2 sl = SL[p];
        const float samp = bf2f(base[o.x]) * w.x + bf2f(base[o.y]) * w.y
                         + bf2f(base[o.z]) * w.z + bf2f(base[o.w]) * w.w;
        acc  += samp * sl.x;
        accm += samp * sl.y;
    }
    outp[(size_t)blk * 256 + tid]  = acc;
    moutp[(size_t)blk * 256 + tid] = accm;
}

// ---------------- Kernel 3: oproj LDS-staged MFMA, BM=128/BN=256, IN-PLACE --------------
// A rows == C rows per block (full-width N) -> no cross-block hazard; all reads precede
// the epilogue writes within the block. Weights converted from f32 in-reg.
__global__ __launch_bounds__(512)
void oproj_lds(const float* __restrict__ R, const float* __restrict__ Wof,
               const float* __restrict__ bias, float* __restrict__ Out)
{
    __shared__ __align__(16) short As[128][72];
    __shared__ __align__(16) short Bs[256][72];
    const int tid  = threadIdx.x;
    const int lane = tid & 63, wid = tid >> 6;       // 8 waves
    const int wm = wid >> 2, wn = wid & 3;           // 2x4 wave grid, 64x64 wave tile
    const int row0 = blockIdx.x * 128;               // 38 blocks (4864 >= 4800, clamp)
    const int l16 = lane & 15, lg = lane >> 4;

    f32x4 acc[4][4] = {};
    for (int k0 = 0; k0 < D; k0 += 64) {
        #pragma unroll
        for (int i = 0; i < 2; ++i) {       // A: 128 rows x 64 f32
            const int t = tid + i * 512;
            const int r = t >> 3, c8 = (t & 7) * 8;
            const int arow = min(row0 + r, NR - 1);
            const float* p = R + (size_t)arow * D + k0 + c8;
            *(bf16x8*)&As[r][c8] = pack8c(*(const f32x4*)p, *(const f32x4*)(p + 4));
        }
        #pragma unroll
        for (int i = 0; i < 4; ++i) {       // B: 256 rows x 64 f32
            const int t = tid + i * 512;
            const int r = t >> 3, c8 = (t & 7) * 8;
            const float* q = Wof + (size_t)r * D + k0 + c8;
            *(bf16x8*)&Bs[r][c8] = pack8c(*(const f32x4*)q, *(const f32x4*)(q + 4));
        }
        __syncthreads();
        #pragma unroll
        for (int kk = 0; kk < 2; ++kk) {
            bf16x8 af[4], bfr[4];
            #pragma unroll
            for (int m = 0; m < 4; ++m)
                af[m] = *(const bf16x8*)&As[wm * 64 + m * 16 + l16][kk * 32 + lg * 8];
            #pragma unroll
            for (int n = 0; n < 4; ++n)
                bfr[n] = *(const bf16x8*)&Bs[wn * 64 + n * 16 + l16][kk * 32 + lg * 8];
            #pragma unroll
            for (int m = 0; m < 4; ++m)
                #pragma unroll
                for (int n = 0; n < 4; ++n)
                    acc[m][n] = __builtin_amdgcn_mfma_f32_16x16x32_bf16(af[m], bfr[n], acc[m][n], 0, 0, 0);
        }
        __syncthreads();
    }
    #pragma unroll
    for (int m = 0; m < 4; ++m) {
        #pragma unroll
        for (int r = 0; r < 4; ++r) {
            const int grow = row0 + wm * 64 + m * 16 + lg * 4 + r;
            if (grow >= NR) continue;
            #pragma unroll
            for (int n = 0; n < 4; ++n) {
                const int gcol = wn * 64 + n * 16 + l16;
                Out[(size_t)grow * D + gcol] = acc[m][n][r] + bias[gcol];
            }
        }
    }
}

extern "C" void kernel_launch(void* const* d_in, const int* in_sizes, int n_in,
                              void* d_out, int out_size, void* d_ws, size_t ws_size,
                              hipStream_t stream)
{
    const float* query        = (const float*)d_in[0];
    const float* value        = (const float*)d_in[1];
    const int*   vshape       = (const int*)d_in[2];
    const unsigned char* vmask= (const unsigned char*)d_in[3];
    const float* vratio       = (const float*)d_in[5];
    const float* refw         = (const float*)d_in[6];
    const float* box_w        = (const float*)d_in[7];
    const float* box_b        = (const float*)d_in[8];
    const float* attn_w       = (const float*)d_in[9];
    const float* attn_b       = (const float*)d_in[10];
    const float* vproj_w      = (const float*)d_in[11];
    const float* vproj_b      = (const float*)d_in[12];
    const float* oproj_w      = (const float*)d_in[13];
    const float* oproj_b      = (const float*)d_in[14];

    unsigned short* vm_b = (unsigned short*)d_ws;      // 8,388,608 bf16 (16.8 MB)
    float* bp = (float*)(vm_b + 8388608);              // 307,200 f32
    float* ap = bp + 307200;                           // 307,200 f32
    // total ws ~19.2 MB

    float* out1 = (float*)d_out;          // output       614,400
    float* out2 = out1 + 614400;          // mask_output  614,400
    float* awo  = out2 + 614400;          // aw repeated  1,228,800

    float* outp  = out1;                  // pre-projection accumulators (in-place oproj)
    float* moutp = out2;

    fat_kernel<<<664, 256, 0, stream>>>(value, vproj_w, vproj_b, vmask, vm_b,
                                        query, box_w, box_b, attn_w, attn_b, bp, ap, awo);
    sample_kernel<<<NQ, 256, 0, stream>>>(vm_b, bp, ap, refw, vratio, vshape, outp, moutp);
    oproj_lds<<<38, 512, 0, stream>>>(out1, oproj_w, oproj_b, out1);
}